// Round 3
// baseline (512.322 us; speedup 1.0000x reference)
//
#include <hip/hip_runtime.h>

typedef __attribute__((ext_vector_type(4))) float  f4;
typedef __attribute__((ext_vector_type(8))) short  bf16x8;
typedef __attribute__((ext_vector_type(4))) float  f32x4;
typedef __attribute__((ext_vector_type(4))) unsigned short us4;
typedef __attribute__((ext_vector_type(4))) unsigned int u32x4;

#define BATCH 64
#define FEAT 2048
#define NC_C 112
#define TE 1024          // 2*E
#define EE 512
#define NCLS 345
#define NCLSP 352
#define KHEAD 57344      // C*E

__device__ __forceinline__ unsigned short f2bf(float f) {
    unsigned u = __float_as_uint(f);
    unsigned r = (u + 0x7FFFu + ((u >> 16) & 1u)) >> 16;
    return (unsigned short)r;
}
__device__ __forceinline__ float bf2f(unsigned short h) {
    return __uint_as_float(((unsigned)h) << 16);
}
// packed f32x2 -> bf16x2 (RNE): low half = cvt(a), high half = cvt(b)
__device__ __forceinline__ unsigned cvtpk(float a, float b) {
    unsigned r;
    asm("v_cvt_pk_bf16_f32 %0, %1, %2" : "=v"(r) : "v"(a), "v"(b));
    return r;
}

// ---------------------------------------------------------------------------
// K0: x (f32) -> xb (bf16), row-major [64][2048]. 64 blocks x 256 thr x 8 elem
// ---------------------------------------------------------------------------
__global__ __launch_bounds__(256) void k_xcast(
    const float* __restrict__ x, unsigned short* __restrict__ xb)
{
    const int i = blockIdx.x * 256 + threadIdx.x;   // 16384 threads
    const f4 v0 = *(const f4*)&x[i * 8];
    const f4 v1 = *(const f4*)&x[i * 8 + 4];
    u32x4 o;
    o[0] = cvtpk(v0[0], v0[1]);
    o[1] = cvtpk(v0[2], v0[3]);
    o[2] = cvtpk(v1[0], v1[1]);
    o[3] = cvtpk(v1[2], v1[3]);
    *(u32x4*)&xb[i * 8] = o;
}

// ---------------------------------------------------------------------------
// K1: embeddings = x @ W_emb[c] + b_emb. NO LDS, NO BARRIERS.
// B-fragments loaded directly from W_emb natural [k][n] layout (8 dword
// loads/frag, each instr = 4 fully-used 64B lines, each line read once).
// A-fragments 16B contiguous from pre-cast xb. 1-step-ahead register
// pipeline; compiler emits counted vmcnt (never drains to 0 — no barriers).
// grid 896 = 112 c * 8 n-tiles; block 256 = 4 waves, wave owns 64 x 32 out.
// ---------------------------------------------------------------------------
__global__ __launch_bounds__(256) void k_emb(
    const unsigned short* __restrict__ xb, const float* __restrict__ W_emb,
    const float* __restrict__ b_emb, unsigned short* __restrict__ emb_bf)
{
    const int tid = threadIdx.x;
    const int c  = blockIdx.x >> 3;
    const int n0 = (blockIdx.x & 7) * 128;
    const float* __restrict__ Wc = W_emb + (size_t)c * (FEAT * TE);

    const int w = tid >> 6, l = tid & 63;
    const int lm = l & 15, kg = l >> 4;          // kg in 0..3
    const int colbase = n0 + w * 32 + lm;        // + nf*16

    const float* __restrict__ bp = Wc + (size_t)(kg * 8) * TE + colbase;
    const unsigned short* __restrict__ ap = xb + (size_t)lm * FEAT + kg * 8;

    f32x4 acc[4][2];
#pragma unroll
    for (int mf = 0; mf < 4; ++mf)
#pragma unroll
        for (int nf = 0; nf < 2; ++nf) acc[mf][nf] = (f32x4){0.f, 0.f, 0.f, 0.f};

    auto loadB = [&](float* B, int s) {
        const float* p = bp + (size_t)s * 32 * TE;
#pragma unroll
        for (int nf = 0; nf < 2; ++nf)
#pragma unroll
            for (int r = 0; r < 8; ++r)
                B[nf * 8 + r] = p[(size_t)r * TE + nf * 16];
    };
    auto loadA = [&](bf16x8* A, int s) {
        const unsigned short* p = ap + s * 32;
#pragma unroll
        for (int mf = 0; mf < 4; ++mf)
            A[mf] = *(const bf16x8*)(p + mf * 16 * FEAT);
    };
    auto compute = [&](const float* B, const bf16x8* A) {
        bf16x8 bfr[2];
#pragma unroll
        for (int nf = 0; nf < 2; ++nf) {
            u32x4 q;
            q[0] = cvtpk(B[nf * 8 + 0], B[nf * 8 + 1]);
            q[1] = cvtpk(B[nf * 8 + 2], B[nf * 8 + 3]);
            q[2] = cvtpk(B[nf * 8 + 4], B[nf * 8 + 5]);
            q[3] = cvtpk(B[nf * 8 + 6], B[nf * 8 + 7]);
            bfr[nf] = __builtin_bit_cast(bf16x8, q);
        }
#pragma unroll
        for (int mf = 0; mf < 4; ++mf)
#pragma unroll
            for (int nf = 0; nf < 2; ++nf)
                acc[mf][nf] = __builtin_amdgcn_mfma_f32_16x16x32_bf16(
                    A[mf], bfr[nf], acc[mf][nf], 0, 0, 0);
    };

    float   Bc[16], Bn[16];
    bf16x8  Ac[4],  An[4];
    loadB(Bc, 0);
    loadA(Ac, 0);

#pragma unroll 1
    for (int s = 0; s < 64; s += 2) {
        loadB(Bn, s + 1);            // issue next-step loads first
        loadA(An, s + 1);
        compute(Bc, Ac);             // waits only on Bc/Ac regs (counted vmcnt)
        if (s + 2 < 64) {
            loadB(Bc, s + 2);
            loadA(Ac, s + 2);
        }
        compute(Bn, An);
    }

    // epilogue: + b_emb, store bf16 (emb layout [b][c][e])
#pragma unroll
    for (int mf = 0; mf < 4; ++mf)
#pragma unroll
        for (int nf = 0; nf < 2; ++nf) {
            const int ng = n0 + w * 32 + nf * 16 + lm;
            const float bias = b_emb[c * TE + ng];
#pragma unroll
            for (int r = 0; r < 4; ++r) {
                const int bb = mf * 16 + kg * 4 + r;
                const float v = acc[mf][nf][r] + bias;
                emb_bf[((size_t)bb * NC_C + c) * TE + ng] = f2bf(v);
            }
        }
}

// ---------------------------------------------------------------------------
// K2: p_int = sigmoid(emb . W_pint + b_pint); mixed = p*pos + (1-p)*neg
// one wave per (b,c); grid 1792 * 256
// ---------------------------------------------------------------------------
__global__ __launch_bounds__(256) void k_mix(
    const unsigned short* __restrict__ emb_bf, const float* __restrict__ W_pint,
    const float* __restrict__ b_pint, float* __restrict__ flat_out,
    float* __restrict__ p_out)
{
    const int tid = threadIdx.x;
    const int l = tid & 63, w = tid >> 6;
    const int pidx = blockIdx.x * 4 + w;           // 0..7167
    const int b = pidx / NC_C, c = pidx - b * NC_C;

    const unsigned short* __restrict__ row = emb_bf + ((size_t)b * NC_C + c) * TE;
    const float* __restrict__ wp = W_pint + c * TE;

    float vals[16];
    float dot = 0.f;
#pragma unroll
    for (int i = 0; i < 4; ++i) {
        const int e = 4 * l + 256 * i;
        us4 u = *(const us4*)&row[e];
        f4  wv = *(const f4*)&wp[e];
#pragma unroll
        for (int j = 0; j < 4; ++j) {
            float f = bf2f(u[j]);
            vals[i * 4 + j] = f;
            dot += f * wv[j];
        }
    }
#pragma unroll
    for (int m = 32; m >= 1; m >>= 1) dot += __shfl_xor(dot, m);
    const float logit = dot + b_pint[c];
    const float p = 1.f / (1.f + __expf(-logit));
    if (l == 0) p_out[b * NC_C + c] = p;

    float* __restrict__ fo = flat_out + (size_t)b * KHEAD + c * EE;
#pragma unroll
    for (int i = 0; i < 2; ++i) {
        const int e = 4 * l + 256 * i;
        f4 m;
#pragma unroll
        for (int j = 0; j < 4; ++j)
            m[j] = p * vals[i * 4 + j] + (1.f - p) * vals[(i + 2) * 4 + j];
        *(f4*)&fo[e] = m;
    }
}

// ---------------------------------------------------------------------------
// K3: partial = flat @ W_head for this block's K-slice -> pbuf[blk][64][352]
// atomic-free split-K; nsteps*32 K per block
// ---------------------------------------------------------------------------
__global__ __launch_bounds__(256) void k_head(
    const float* __restrict__ flat, const float* __restrict__ W_head,
    float* __restrict__ pbuf, int nsteps)
{
    __shared__ __align__(16) unsigned short Blds[NCLSP * 40];  // [n][k] swizzled

    const int tid = threadIdx.x;
    const int w = tid >> 6, l = tid & 63;
    const int k0 = blockIdx.x * (nsteps * 32);

    f32x4 acc[22];
#pragma unroll
    for (int i = 0; i < 22; ++i) acc[i] = (f32x4){0.f, 0.f, 0.f, 0.f};

    for (int s = 0; s < nsteps; ++s) {
        const int kb = k0 + s * 32;
        __syncthreads();
        for (int idx = tid; idx < 32 * NCLSP; idx += 256) {
            const int k = idx / NCLSP;
            const int n = idx - k * NCLSP;
            const float v = (n < NCLS) ? W_head[(size_t)(kb + k) * NCLS + n] : 0.f;
            Blds[n * 40 + ((((k >> 3) ^ ((n >> 2) & 3)) << 3) | (k & 7))] = f2bf(v);
        }
        __syncthreads();

        const float* __restrict__ ap =
            flat + (size_t)(w * 16 + (l & 15)) * KHEAD + kb + (l >> 4) * 8;
        f4 af0 = *(const f4*)ap;
        f4 af1 = *(const f4*)(ap + 4);
        u32x4 pq;
        pq[0] = cvtpk(af0[0], af0[1]); pq[1] = cvtpk(af0[2], af0[3]);
        pq[2] = cvtpk(af1[0], af1[1]); pq[3] = cvtpk(af1[2], af1[3]);
        bf16x8 a = __builtin_bit_cast(bf16x8, pq);

#pragma unroll
        for (int nf = 0; nf < 22; ++nf) {
            const int n = nf * 16 + (l & 15);
            bf16x8 bfr = *(const bf16x8*)&Blds[n * 40 + (((l >> 4) ^ ((n >> 2) & 3)) << 3)];
            acc[nf] = __builtin_amdgcn_mfma_f32_16x16x32_bf16(a, bfr, acc[nf], 0, 0, 0);
        }
    }

    float* __restrict__ pb = pbuf + (size_t)blockIdx.x * (64 * NCLSP);
#pragma unroll
    for (int nf = 0; nf < 22; ++nf) {
        const int n = nf * 16 + (l & 15);
#pragma unroll
        for (int r = 0; r < 4; ++r) {
            const int row = w * 16 + (l >> 4) * 4 + r;
            pb[row * NCLSP + n] = acc[nf][r];
        }
    }
}

// ---------------------------------------------------------------------------
// K4: final = b_head + sum_p partial[p]   (deterministic reduce)
// ---------------------------------------------------------------------------
__global__ __launch_bounds__(256) void k_reduce(
    const float* __restrict__ pbuf, const float* __restrict__ b_head,
    float* __restrict__ final_out, int nb)
{
    const int i = blockIdx.x * 256 + threadIdx.x;
    if (i >= BATCH * NCLS) return;
    const int m = i / NCLS, n = i - m * NCLS;
    float s = b_head[n];
    for (int p = 0; p < nb; ++p)
        s += pbuf[((size_t)p * 64 + m) * NCLSP + n];
    final_out[i] = s;
}

extern "C" void kernel_launch(void* const* d_in, const int* in_sizes, int n_in,
                              void* d_out, int out_size, void* d_ws, size_t ws_size,
                              hipStream_t stream) {
    const float* x      = (const float*)d_in[0];
    const float* W_emb  = (const float*)d_in[1];
    const float* b_emb  = (const float*)d_in[2];
    const float* W_pint = (const float*)d_in[3];
    const float* b_pint = (const float*)d_in[4];
    const float* W_head = (const float*)d_in[5];
    const float* b_head = (const float*)d_in[6];

    float* out       = (float*)d_out;
    float* final_out = out;                                   // 64*345
    float* flat      = out + BATCH * NCLS;                    // 64*57344
    float* p_out     = out + BATCH * NCLS + BATCH * KHEAD;    // 64*112

    // ws layout: [0 .. 20.2MB) emb_bf (14.3MB) then overlaid by pbuf (20.2MB);
    // [32MB ..) xb (256KB). ws is ~3.7GB per harness poison fill.
    unsigned short* emb_bf = (unsigned short*)d_ws;
    float* pbuf = (float*)d_ws;
    unsigned short* xb = (unsigned short*)((char*)d_ws + (32u << 20));

    int NB, nsteps;
    const size_t need224 = (size_t)224 * 64 * NCLSP * sizeof(float) + (32u << 20);
    if (ws_size >= need224) { NB = 224; nsteps = 8; }
    else                    { NB = 128; nsteps = 14; }

    k_xcast<<<64, 256, 0, stream>>>(x, xb);
    k_emb<<<NC_C * 8, 256, 0, stream>>>(xb, W_emb, b_emb, emb_bf);
    k_mix<<<(BATCH * NC_C) / 4, 256, 0, stream>>>(emb_bf, W_pint, b_pint, flat, p_out);
    k_head<<<NB, 256, 0, stream>>>(flat, W_head, pbuf, nsteps);
    k_reduce<<<(BATCH * NCLS + 255) / 256, 256, 0, stream>>>(pbuf, b_head, final_out, NB);
}

// Round 6
// 478.749 us; speedup vs baseline: 1.0701x; 1.0701x over previous
//
#include <hip/hip_runtime.h>

typedef __attribute__((ext_vector_type(4))) float  f4;
typedef __attribute__((ext_vector_type(8))) short  bf16x8;
typedef __attribute__((ext_vector_type(4))) float  f32x4;
typedef __attribute__((ext_vector_type(4))) unsigned short us4;
typedef __attribute__((ext_vector_type(2))) unsigned int u32x2;
typedef __attribute__((ext_vector_type(4))) unsigned int u32x4;

#define BATCH 64
#define FEAT 2048
#define NC_C 112
#define TE 1024          // 2*E
#define EE 512
#define NCLS 345
#define NCLSP 352
#define KHEAD 57344      // C*E

__device__ __forceinline__ unsigned short f2bf(float f) {
    unsigned u = __float_as_uint(f);
    unsigned r = (u + 0x7FFFu + ((u >> 16) & 1u)) >> 16;
    return (unsigned short)r;
}
__device__ __forceinline__ float bf2f(unsigned short h) {
    return __uint_as_float(((unsigned)h) << 16);
}
__device__ __forceinline__ unsigned cvtpk(float a, float b) {
    unsigned r;
    asm("v_cvt_pk_bf16_f32 %0, %1, %2" : "=v"(r) : "v"(a), "v"(b));
    return r;
}

// ---------------------------------------------------------------------------
// K1: split-K partial GEMM, staging/fragment/store code IDENTICAL to the
// verified R1/R2 kernel; only change: K restricted to [ks*256, ks*256+256)
// and output is bf16 partials pbe[ks][m][c][e] (bias moved to k_mix).
// grid 7168 = 112c * 8 n-tiles * 8 ks; block 256 (4 waves, 2x2 over 64x128).
// ---------------------------------------------------------------------------
__global__ __launch_bounds__(256) void k_emb(
    const float* __restrict__ x, const float* __restrict__ W_emb,
    unsigned short* __restrict__ pbe)
{
    __shared__ __align__(16) unsigned short Alds[64 * 40];   // [row][k] stride 40
    __shared__ __align__(16) unsigned short Blds[128 * 40];  // [n][k] swizzled

    const int tid = threadIdx.x;
    const int bid = blockIdx.x;
    const int c  = bid >> 6;
    const int nt = (bid >> 3) & 7;
    const int ks = bid & 7;
    const int n0 = nt * 128;
    const int kofs = ks * 256;
    const float* __restrict__ Wc = W_emb + (size_t)c * (FEAT * TE);

    const int w = tid >> 6, l = tid & 63;
    const int mbase = (w & 1) * 32, nbase = (w >> 1) * 64;

    const int a_row = tid >> 3;           // 0..31 (+32 second row)
    const int a_k4  = (tid & 7) * 4;
    const int b_kp  = tid >> 4;           // 0..15
    const int b_n4  = (tid & 15) * 4;

    const float* __restrict__ axp = x + (size_t)a_row * FEAT + kofs + a_k4;
    const float* __restrict__ bpp = Wc + (size_t)(kofs + 2 * b_kp) * TE + n0 + b_n4;

    unsigned short* __restrict__ aw0 = &Alds[a_row * 40 + a_k4];
    unsigned short* __restrict__ aw1 = &Alds[(a_row + 32) * 40 + a_k4];
    const int koct = b_kp >> 2, klo = (2 * b_kp) & 7;

    auto ke_load = [&](f4& A0, f4& A1, f4& B0, f4& B1, f4& B2, f4& B3, int kstep) {
        const float* ax_ = axp + kstep * 32;
        A0 = *(const f4*)ax_;
        A1 = *(const f4*)(ax_ + 32 * FEAT);
        const float* bp_ = bpp + (size_t)kstep * 32 * TE;
        B0 = *(const f4*)bp_;         B1 = *(const f4*)(bp_ + TE);
        B2 = *(const f4*)(bp_ + 64);  B3 = *(const f4*)(bp_ + TE + 64);
    };
    auto ke_write = [&](const f4& A0, const f4& A1, const f4& B0, const f4& B1,
                        const f4& B2, const f4& B3) {
        u32x2 v0, v1;
        v0[0] = cvtpk(A0[0], A0[1]); v0[1] = cvtpk(A0[2], A0[3]);
        v1[0] = cvtpk(A1[0], A1[1]); v1[1] = cvtpk(A1[2], A1[3]);
        *(u32x2*)aw0 = v0;
        *(u32x2*)aw1 = v1;
#pragma unroll
        for (int i = 0; i < 4; ++i) {
            int n = b_n4 + i;
            *(unsigned*)&Blds[n * 40 + (((koct ^ ((n >> 2) & 3)) << 3) | klo)] =
                cvtpk(B0[i], B1[i]);
            n += 64;
            *(unsigned*)&Blds[n * 40 + (((koct ^ ((n >> 2) & 3)) << 3) | klo)] =
                cvtpk(B2[i], B3[i]);
        }
    };

    f32x4 acc[2][4];
#pragma unroll
    for (int i = 0; i < 2; ++i)
#pragma unroll
        for (int j = 0; j < 4; ++j) acc[i][j] = (f32x4){0.f, 0.f, 0.f, 0.f};

    auto ke_mfma = [&]() {
        bf16x8 af[2], bfr[4];
#pragma unroll
        for (int si = 0; si < 2; ++si)
            af[si] = *(const bf16x8*)&Alds[(mbase + si * 16 + (l & 15)) * 40 + (l >> 4) * 8];
#pragma unroll
        for (int nf = 0; nf < 4; ++nf) {
            int n = nbase + nf * 16 + (l & 15);
            bfr[nf] = *(const bf16x8*)&Blds[n * 40 + (((l >> 4) ^ ((n >> 2) & 3)) << 3)];
        }
#pragma unroll
        for (int si = 0; si < 2; ++si)
#pragma unroll
            for (int nf = 0; nf < 4; ++nf)
                acc[si][nf] = __builtin_amdgcn_mfma_f32_16x16x32_bf16(
                    af[si], bfr[nf], acc[si][nf], 0, 0, 0);
    };

    f4 a0, a1, p0, p1, p2, p3;
    ke_load(a0, a1, p0, p1, p2, p3, 0);

    for (int s = 0; s < 8; ++s) {
        __syncthreads();
        ke_write(a0, a1, p0, p1, p2, p3);
        __syncthreads();
        if (s < 7) ke_load(a0, a1, p0, p1, p2, p3, s + 1);
        ke_mfma();
    }

    // store bf16 partials: pbe[ks][m][c][e]
#pragma unroll
    for (int si = 0; si < 2; ++si)
#pragma unroll
        for (int nf = 0; nf < 4; ++nf) {
            const int nl = nbase + nf * 16 + (l & 15);
            const int ng = n0 + nl;
#pragma unroll
            for (int r = 0; r < 4; ++r) {
                const int m = mbase + si * 16 + (l >> 4) * 4 + r;
                pbe[((size_t)(ks * 64 + m) * NC_C + c) * TE + ng] = f2bf(acc[si][nf][r]);
            }
        }
}

// ---------------------------------------------------------------------------
// K2: reduce 8 partials + bias -> emb; p_int = sigmoid(emb . W_pint + b);
// mixed = p*pos + (1-p)*neg -> flat. one wave per (b,c)
// ---------------------------------------------------------------------------
__global__ __launch_bounds__(256) void k_mix(
    const unsigned short* __restrict__ pbe, const float* __restrict__ b_emb,
    const float* __restrict__ W_pint, const float* __restrict__ b_pint,
    float* __restrict__ flat_out, float* __restrict__ p_out)
{
    const int tid = threadIdx.x;
    const int l = tid & 63, w = tid >> 6;
    const int pidx = blockIdx.x * 4 + w;
    const int b = pidx / NC_C, c = pidx - b * NC_C;

    float vals[16];
#pragma unroll
    for (int i = 0; i < 4; ++i) {
        const f4 bi = *(const f4*)&b_emb[c * TE + 4 * l + 256 * i];
#pragma unroll
        for (int j = 0; j < 4; ++j) vals[4 * i + j] = bi[j];
    }
#pragma unroll
    for (int ksl = 0; ksl < 8; ++ksl) {
        const unsigned short* __restrict__ rp =
            pbe + ((size_t)(ksl * 64 + b) * NC_C + c) * TE;
#pragma unroll
        for (int i = 0; i < 4; ++i) {
            us4 u = *(const us4*)&rp[4 * l + 256 * i];
#pragma unroll
            for (int j = 0; j < 4; ++j) vals[4 * i + j] += bf2f(u[j]);
        }
    }

    const float* __restrict__ wp = W_pint + c * TE;
    float dot = 0.f;
#pragma unroll
    for (int i = 0; i < 4; ++i) {
        const f4 wv = *(const f4*)&wp[4 * l + 256 * i];
#pragma unroll
        for (int j = 0; j < 4; ++j) dot += vals[4 * i + j] * wv[j];
    }
#pragma unroll
    for (int m = 32; m >= 1; m >>= 1) dot += __shfl_xor(dot, m);
    const float logit = dot + b_pint[c];
    const float p = 1.f / (1.f + __expf(-logit));
    if (l == 0) p_out[b * NC_C + c] = p;

    float* __restrict__ fo = flat_out + (size_t)b * KHEAD + c * EE;
#pragma unroll
    for (int i = 0; i < 2; ++i) {
        f4 m;
#pragma unroll
        for (int j = 0; j < 4; ++j)
            m[j] = p * vals[i * 4 + j] + (1.f - p) * vals[(i + 2) * 4 + j];
        *(f4*)&fo[4 * l + 256 * i] = m;
    }
}

// ---------------------------------------------------------------------------
// K3: partial = flat @ W_head (split-K, atomic-free) -> pbuf[blk][64][352]
// ---------------------------------------------------------------------------
__global__ __launch_bounds__(256) void k_head(
    const float* __restrict__ flat, const float* __restrict__ W_head,
    float* __restrict__ pbuf, int nsteps)
{
    __shared__ __align__(16) unsigned short Blds[NCLSP * 40];

    const int tid = threadIdx.x;
    const int w = tid >> 6, l = tid & 63;
    const int k0 = blockIdx.x * (nsteps * 32);

    f32x4 acc[22];
#pragma unroll
    for (int i = 0; i < 22; ++i) acc[i] = (f32x4){0.f, 0.f, 0.f, 0.f};

    for (int s = 0; s < nsteps; ++s) {
        const int kb = k0 + s * 32;
        __syncthreads();
        for (int idx = tid; idx < 32 * NCLSP; idx += 256) {
            const int k = idx / NCLSP;
            const int n = idx - k * NCLSP;
            const float v = (n < NCLS) ? W_head[(size_t)(kb + k) * NCLS + n] : 0.f;
            Blds[n * 40 + ((((k >> 3) ^ ((n >> 2) & 3)) << 3) | (k & 7))] = f2bf(v);
        }
        __syncthreads();

        const float* __restrict__ ap =
            flat + (size_t)(w * 16 + (l & 15)) * KHEAD + kb + (l >> 4) * 8;
        f4 af0 = *(const f4*)ap;
        f4 af1 = *(const f4*)(ap + 4);
        u32x4 pq;
        pq[0] = cvtpk(af0[0], af0[1]); pq[1] = cvtpk(af0[2], af0[3]);
        pq[2] = cvtpk(af1[0], af1[1]); pq[3] = cvtpk(af1[2], af1[3]);
        bf16x8 a = __builtin_bit_cast(bf16x8, pq);

#pragma unroll
        for (int nf = 0; nf < 22; ++nf) {
            const int n = nf * 16 + (l & 15);
            bf16x8 bfr = *(const bf16x8*)&Blds[n * 40 + (((l >> 4) ^ ((n >> 2) & 3)) << 3)];
            acc[nf] = __builtin_amdgcn_mfma_f32_16x16x32_bf16(a, bfr, acc[nf], 0, 0, 0);
        }
    }

    float* __restrict__ pb = pbuf + (size_t)blockIdx.x * (64 * NCLSP);
#pragma unroll
    for (int nf = 0; nf < 22; ++nf) {
        const int n = nf * 16 + (l & 15);
#pragma unroll
        for (int r = 0; r < 4; ++r) {
            const int row = w * 16 + (l >> 4) * 4 + r;
            pb[row * NCLSP + n] = acc[nf][r];
        }
    }
}

// ---------------------------------------------------------------------------
// K4: final = b_head + sum_p partial[p]
// ---------------------------------------------------------------------------
__global__ __launch_bounds__(256) void k_reduce(
    const float* __restrict__ pbuf, const float* __restrict__ b_head,
    float* __restrict__ final_out, int nb)
{
    const int i = blockIdx.x * 256 + threadIdx.x;
    if (i >= BATCH * NCLS) return;
    const int m = i / NCLS, n = i - m * NCLS;
    float s = b_head[n];
    for (int p = 0; p < nb; ++p)
        s += pbuf[((size_t)p * 64 + m) * NCLSP + n];
    final_out[i] = s;
}

extern "C" void kernel_launch(void* const* d_in, const int* in_sizes, int n_in,
                              void* d_out, int out_size, void* d_ws, size_t ws_size,
                              hipStream_t stream) {
    const float* x      = (const float*)d_in[0];
    const float* W_emb  = (const float*)d_in[1];
    const float* b_emb  = (const float*)d_in[2];
    const float* W_pint = (const float*)d_in[3];
    const float* b_pint = (const float*)d_in[4];
    const float* W_head = (const float*)d_in[5];
    const float* b_head = (const float*)d_in[6];

    float* out       = (float*)d_out;
    float* final_out = out;                                   // 64*345
    float* flat      = out + BATCH * NCLS;                    // 64*57344
    float* p_out     = out + BATCH * NCLS + BATCH * KHEAD;    // 64*112

    // ws layout: [0,112MiB) emb bf16 partials; [120MiB,+19.3MiB) head partials
    unsigned short* pbe = (unsigned short*)d_ws;
    float* pbuf_h = (float*)((char*)d_ws + (size_t)120 * 1024 * 1024);

    const int NB = 224, nsteps = 8;

    k_emb<<<NC_C * 8 * 8, 256, 0, stream>>>(x, W_emb, pbe);
    k_mix<<<(BATCH * NC_C) / 4, 256, 0, stream>>>(pbe, b_emb, W_pint, b_pint, flat, p_out);
    k_head<<<NB, 256, 0, stream>>>(flat, W_head, pbuf_h, nsteps);
    k_reduce<<<(BATCH * NCLS + 255) / 256, 256, 0, stream>>>(pbuf_h, b_head, final_out, NB);
}